// Round 24
// baseline (32.332 us; speedup 1.0000x reference)
//
#include <hip/hip_runtime.h>
#include <math.h>

// Dims (fixed per reference)
#define B   128
#define L   50
#define V   100000
#define ND  4
#define D   64

// out layout: P_v (B*V) | infomax_loss (1) | gnn (B*ND*L*D)

typedef __attribute__((ext_vector_type(8))) short s8v;   // 8 bf16 (4 VGPR)
typedef __attribute__((ext_vector_type(4))) float f4v;   // MFMA acc

#define NVB ((V + 127) / 128)                 // 782 P_v blocks
#define NIB (B)                               // 128 infomax blocks
#define NGNN (B * ND * L * (D / 4))           // 409600 gnn float4s

__device__ __forceinline__ float log_sigmoid(float x) {
    if (x >= 0.f) return -log1pf(expf(-x));
    return x - log1pf(expf(x));
}

__device__ __forceinline__ short bf16rne(float x) {
    unsigned u = __float_as_uint(x);
    unsigned r = u + 0x7FFFu + ((u >> 16) & 1u);
    return (short)(r >> 16);
}
__device__ __forceinline__ float bf16f(short s) {
    return __uint_as_float(((unsigned)(unsigned short)s) << 16);
}

// K1c: lean prologue — gather, masked-mean gr, last, u = W_im@gr,
// h = tanh([gr|last]@W_pvsd + b) as bf16 hi/lo. Zero-inits loss.
__global__ __launch_bounds__(256) void k1_compute(
    const int* __restrict__ nodes, const int* __restrict__ mask,
    const int* __restrict__ sli, const float* __restrict__ emb_i,
    const float* __restrict__ W_pvsd, const float* __restrict__ b_pvsd,
    const float* __restrict__ W_im,
    float* __restrict__ u, short* __restrict__ hh, short* __restrict__ hl,
    float* __restrict__ loss)
{
    const int b = blockIdx.x;
    const int t = threadIdx.x;
    if (b == 0 && t == 0) loss[0] = 0.f;
    __shared__ int   s_nodes[L];
    __shared__ float s_mask[L];
    __shared__ float s_part[4][D];
    __shared__ float s_gr[D], s_last[D];
    if (t < L) {
        s_nodes[t] = nodes[b * L + t];
        s_mask[t]  = (float)mask[b * L + t];
    }
    __syncthreads();
    const int d  = t & 63;
    const int l0 = t >> 6;
    float acc = 0.f;
    for (int l = l0; l < L; l += 4)
        acc += s_mask[l] * emb_i[(size_t)s_nodes[l] * D + d];
    s_part[l0][d] = acc;
    __syncthreads();
    if (t < D) {
        float msum = 0.f;
        for (int l = 0; l < L; ++l) msum += s_mask[l];
        float s = s_part[0][t] + s_part[1][t] + s_part[2][t] + s_part[3][t];
        s_gr[t]   = s / msum;
        s_last[t] = emb_i[(size_t)s_nodes[sli[b]] * D + t];
    }
    __syncthreads();
    if (t < D) {
        float uu = 0.f;
        #pragma unroll
        for (int e = 0; e < D; ++e) uu += W_im[t * D + e] * s_gr[e];
        u[b * D + t] = uu;
        float pre = b_pvsd[t];
        #pragma unroll
        for (int k = 0; k < D; ++k) pre += s_gr[k]   * W_pvsd[k * D + t];
        #pragma unroll
        for (int k = 0; k < D; ++k) pre += s_last[k] * W_pvsd[(D + k) * D + t];
        float hv = tanhf(pre);
        short hi = bf16rne(hv);
        short lo = bf16rne(hv - bf16f(hi));
        hh[b * D + t] = hi;
        hl[b * D + t] = lo;
    }
}

// K5m, one dispatch, two block roles:
//   [0, NVB):       P_v = h @ emb^T (bf16x3 MFMA, h in LDS, VT=2). R24
//                   overlap fixes: (1) the 8 emb f4v loads are issued
//                   BEFORE the LDS stage — the barrier's mandatory
//                   vmcnt(0) drain then covers their ~700cy HBM latency
//                   instead of exposing it post-barrier; (2) the gnn
//                   broadcast-write is folded in grid-stride pre-barrier,
//                   overlapping the same drain window (and dropping 1600
//                   trivial blocks from the dispatch).
//   [NVB, NVB+NIB): infomax partials (session rows direct from emb).
__global__ __launch_bounds__(256, 4) void k5_mfma(
    const short* __restrict__ hh, const short* __restrict__ hl,
    const float* __restrict__ emb_i, const float* __restrict__ u,
    const int* __restrict__ nodes, float* __restrict__ gnn,
    float* __restrict__ pv, float* __restrict__ loss)
{
    __shared__ short slds[B * 128];   // 32KB

    const int t = threadIdx.x;

    if (blockIdx.x >= NVB) {
        // ---- infomax branch (former k3), session rows from emb ----
        const int b = blockIdx.x - NVB;
        float* s_up = reinterpret_cast<float*>(slds);        // [D]
        float* s_un = s_up + D;                              // [D]
        int*   s_nd = reinterpret_cast<int*>(s_un + D);      // [L]
        if (t < D) {
            const int bm1 = (b + B - 1) % B;
            s_up[t] = u[b * D + t];
            s_un[t] = u[bm1 * D + t];
        }
        if (t < L) s_nd[t] = nodes[b * L + t];
        __syncthreads();
        if (t < 64) {
            float lsp = 0.f, lsn = 0.f;
            if (t < L) {
                const float* se = emb_i + (size_t)s_nd[t] * D;   // == gnn n=0
                float sp = 0.f, sn = 0.f;
                #pragma unroll
                for (int d2 = 0; d2 < D; ++d2) {
                    float vv = se[d2];
                    sp += vv * s_up[d2];
                    sn += vv * s_un[d2];
                }
                lsp = log_sigmoid(sp);
                lsn = log_sigmoid(-sn);
            }
            float tot = lsp + lsn;
            for (int off = 32; off > 0; off >>= 1) tot += __shfl_down(tot, off);
            if (t == 0) atomicAdd(loss, -tot / (float)(B * L));
        }
        return;
    }

    // ---- P_v branch ----
    const int lane = t & 63;
    const int wid  = t >> 6;
    const int lm   = lane & 15;
    const int lg   = lane >> 4;
    const int v0   = (blockIdx.x * 8 + wid * 2) * 16;   // two tiles: v0, v0+16
    const int vcA  = v0 + lm;
    const int vcB  = v0 + 16 + lm;
    const int vldA = vcA < V ? vcA : (V - 1);
    const int vldB = vcB < V ? vcB : (V - 1);

    // (1) emb loads FIRST — independent of the stage; barrier drain hides them
    const float* epA = emb_i + (size_t)vldA * D + 8 * lg;
    const float* epB = emb_i + (size_t)vldB * D + 8 * lg;
    f4v ea0 = *(const f4v*)(epA),      ea1 = *(const f4v*)(epA + 4);
    f4v ea2 = *(const f4v*)(epA + 32), ea3 = *(const f4v*)(epA + 36);
    f4v eb0 = *(const f4v*)(epB),      eb1 = *(const f4v*)(epB + 4);
    f4v eb2 = *(const f4v*)(epB + 32), eb3 = *(const f4v*)(epB + 36);

    // (2) gnn broadcast-write, grid-stride over the P_v blocks (2-3/thread)
    for (int g = blockIdx.x * 256 + t; g < NGNN; g += NVB * 256) {
        const int d4   = g & (D / 4 - 1);
        const int rest = g >> 4;
        const int l    = rest % L;
        const int b    = (rest / L) >> 2;
        const int node = nodes[b * L + l];
        reinterpret_cast<float4*>(gnn)[g] =
            reinterpret_cast<const float4*>(emb_i)[node * (D / 4) + d4];
    }

    // stage h-panel into LDS (XOR-swizzled quads)
    #pragma unroll
    for (int k = 0; k < 8; ++k) {
        const int i   = k * 256 + t;          // quad index 0..2047
        const int row = i >> 4;
        const int q   = i & 15;
        const int p   = (q & 8) | ((q & 7) ^ (row & 7));
        const short* src = (q < 8 ? hh : hl) + row * D + (q & 7) * 8;
        *(s8v*)(&slds[row * 128 + p * 8]) = *(const s8v*)(src);
    }
    __syncthreads();

    s8v Ahi0, Alo0, Ahi1, Alo1;
    s8v Bhi0, Blo0, Bhi1, Blo1;
    #pragma unroll
    for (int i = 0; i < 4; ++i) {
        { float x = ea0[i]; short h = bf16rne(x); Ahi0[i]   = h; Alo0[i]   = bf16rne(x - bf16f(h)); }
        { float x = ea1[i]; short h = bf16rne(x); Ahi0[i+4] = h; Alo0[i+4] = bf16rne(x - bf16f(h)); }
        { float x = ea2[i]; short h = bf16rne(x); Ahi1[i]   = h; Alo1[i]   = bf16rne(x - bf16f(h)); }
        { float x = ea3[i]; short h = bf16rne(x); Ahi1[i+4] = h; Alo1[i+4] = bf16rne(x - bf16f(h)); }
        { float x = eb0[i]; short h = bf16rne(x); Bhi0[i]   = h; Blo0[i]   = bf16rne(x - bf16f(h)); }
        { float x = eb1[i]; short h = bf16rne(x); Bhi0[i+4] = h; Blo0[i+4] = bf16rne(x - bf16f(h)); }
        { float x = eb2[i]; short h = bf16rne(x); Bhi1[i]   = h; Blo1[i]   = bf16rne(x - bf16f(h)); }
        { float x = eb3[i]; short h = bf16rne(x); Bhi1[i+4] = h; Blo1[i+4] = bf16rne(x - bf16f(h)); }
    }

    #pragma unroll
    for (int bt = 0; bt < 8; ++bt) {
        const int row = 16 * bt + lm;
        const int s   = lm & 7;
        const short* base = &slds[row * 128];
        s8v ah0 = *(const s8v*)(base + (((lg    ) ^ s) * 8));
        s8v ah1 = *(const s8v*)(base + (((lg + 4) ^ s) * 8));
        s8v al0 = *(const s8v*)(base + 64 + (((lg    ) ^ s) * 8));
        s8v al1 = *(const s8v*)(base + 64 + (((lg + 4) ^ s) * 8));
        f4v cA0 = {0.f,0.f,0.f,0.f}, cA1 = {0.f,0.f,0.f,0.f};
        f4v cB0 = {0.f,0.f,0.f,0.f}, cB1 = {0.f,0.f,0.f,0.f};
        cA0 = __builtin_amdgcn_mfma_f32_16x16x32_bf16(ah0, Ahi0, cA0, 0, 0, 0);
        cA1 = __builtin_amdgcn_mfma_f32_16x16x32_bf16(ah1, Ahi1, cA1, 0, 0, 0);
        cB0 = __builtin_amdgcn_mfma_f32_16x16x32_bf16(ah0, Bhi0, cB0, 0, 0, 0);
        cB1 = __builtin_amdgcn_mfma_f32_16x16x32_bf16(ah1, Bhi1, cB1, 0, 0, 0);
        cA0 = __builtin_amdgcn_mfma_f32_16x16x32_bf16(ah0, Alo0, cA0, 0, 0, 0);
        cA1 = __builtin_amdgcn_mfma_f32_16x16x32_bf16(ah1, Alo1, cA1, 0, 0, 0);
        cB0 = __builtin_amdgcn_mfma_f32_16x16x32_bf16(ah0, Blo0, cB0, 0, 0, 0);
        cB1 = __builtin_amdgcn_mfma_f32_16x16x32_bf16(ah1, Blo1, cB1, 0, 0, 0);
        cA0 = __builtin_amdgcn_mfma_f32_16x16x32_bf16(al0, Ahi0, cA0, 0, 0, 0);
        cA1 = __builtin_amdgcn_mfma_f32_16x16x32_bf16(al1, Ahi1, cA1, 0, 0, 0);
        cB0 = __builtin_amdgcn_mfma_f32_16x16x32_bf16(al0, Bhi0, cB0, 0, 0, 0);
        cB1 = __builtin_amdgcn_mfma_f32_16x16x32_bf16(al1, Bhi1, cB1, 0, 0, 0);
        const int br = 16 * bt + 4 * lg;
        if (vcA < V) {
            pv[(size_t)(br + 0) * V + vcA] = cA0[0] + cA1[0];
            pv[(size_t)(br + 1) * V + vcA] = cA0[1] + cA1[1];
            pv[(size_t)(br + 2) * V + vcA] = cA0[2] + cA1[2];
            pv[(size_t)(br + 3) * V + vcA] = cA0[3] + cA1[3];
        }
        if (vcB < V) {
            pv[(size_t)(br + 0) * V + vcB] = cB0[0] + cB1[0];
            pv[(size_t)(br + 1) * V + vcB] = cB0[1] + cB1[1];
            pv[(size_t)(br + 2) * V + vcB] = cB0[2] + cB1[2];
            pv[(size_t)(br + 3) * V + vcB] = cB0[3] + cB1[3];
        }
    }
}

extern "C" void kernel_launch(void* const* d_in, const int* in_sizes, int n_in,
                              void* d_out, int out_size, void* d_ws, size_t ws_size,
                              hipStream_t stream)
{
    const int*   nodes  = (const int*)d_in[0];
    const int*   sli    = (const int*)d_in[4];
    const int*   mask   = (const int*)d_in[6];
    const float* emb_i  = (const float*)d_in[7];
    const float* W_pvsd = (const float*)d_in[13];
    const float* b_pvsd = (const float*)d_in[14];
    const float* W_im   = (const float*)d_in[15];

    float* pv   = (float*)d_out;               // B*V
    float* loss = pv + (size_t)B * V;          // 1
    float* gnn  = loss + 1;                    // B*ND*L*D

    float* ws = (float*)d_ws;
    float* u  = ws;                            // B*D floats
    short* hh = (short*)(u + B * D);           // B*D bf16 hi
    short* hl = hh + B * D;                    // B*D bf16 lo

    k1_compute<<<B, 256, 0, stream>>>(nodes, mask, sli, emb_i, W_pvsd, b_pvsd,
                                      W_im, u, hh, hl, loss);
    k5_mfma<<<NVB + NIB, 256, 0, stream>>>(hh, hl, emb_i, u, nodes,
                                           gnn, pv, loss);
}

// Round 26
// 29.491 us; speedup vs baseline: 1.0963x; 1.0963x over previous
//
#include <hip/hip_runtime.h>
#include <math.h>

// Dims (fixed per reference)
#define B   128
#define L   50
#define V   100000
#define ND  4
#define D   64

// out layout: P_v (B*V) | infomax_loss (1) | gnn (B*ND*L*D)

typedef __attribute__((ext_vector_type(8))) short s8v;   // 8 bf16 (4 VGPR)
typedef __attribute__((ext_vector_type(4))) float f4v;   // MFMA acc

#define NVB ((V + 127) / 128)                 // 782 P_v blocks
#define NIB (B)                               // 128 infomax blocks
#define NGB ((B * ND * L * (D / 4)) / 256)    // 1600 gnn-write blocks

__device__ __forceinline__ float log_sigmoid(float x) {
    if (x >= 0.f) return -log1pf(expf(-x));
    return x - log1pf(expf(x));
}

__device__ __forceinline__ short bf16rne(float x) {
    unsigned u = __float_as_uint(x);
    unsigned r = u + 0x7FFFu + ((u >> 16) & 1u);
    return (short)(r >> 16);
}
__device__ __forceinline__ float bf16f(short s) {
    return __uint_as_float(((unsigned)(unsigned short)s) << 16);
}

// K1c: lean prologue — gather, masked-mean gr, last, u = W_im@gr,
// h = tanh([gr|last]@W_pvsd + b) as bf16 hi/lo. Zero-inits loss.
__global__ __launch_bounds__(256) void k1_compute(
    const int* __restrict__ nodes, const int* __restrict__ mask,
    const int* __restrict__ sli, const float* __restrict__ emb_i,
    const float* __restrict__ W_pvsd, const float* __restrict__ b_pvsd,
    const float* __restrict__ W_im,
    float* __restrict__ u, short* __restrict__ hh, short* __restrict__ hl,
    float* __restrict__ loss)
{
    const int b = blockIdx.x;
    const int t = threadIdx.x;
    if (b == 0 && t == 0) loss[0] = 0.f;
    __shared__ int   s_nodes[L];
    __shared__ float s_mask[L];
    __shared__ float s_part[4][D];
    __shared__ float s_gr[D], s_last[D];
    if (t < L) {
        s_nodes[t] = nodes[b * L + t];
        s_mask[t]  = (float)mask[b * L + t];
    }
    __syncthreads();
    const int d  = t & 63;
    const int l0 = t >> 6;
    float acc = 0.f;
    for (int l = l0; l < L; l += 4)
        acc += s_mask[l] * emb_i[(size_t)s_nodes[l] * D + d];
    s_part[l0][d] = acc;
    __syncthreads();
    if (t < D) {
        float msum = 0.f;
        for (int l = 0; l < L; ++l) msum += s_mask[l];
        float s = s_part[0][t] + s_part[1][t] + s_part[2][t] + s_part[3][t];
        s_gr[t]   = s / msum;
        s_last[t] = emb_i[(size_t)s_nodes[sli[b]] * D + t];
    }
    __syncthreads();
    if (t < D) {
        float uu = 0.f;
        #pragma unroll
        for (int e = 0; e < D; ++e) uu += W_im[t * D + e] * s_gr[e];
        u[b * D + t] = uu;
        float pre = b_pvsd[t];
        #pragma unroll
        for (int k = 0; k < D; ++k) pre += s_gr[k]   * W_pvsd[k * D + t];
        #pragma unroll
        for (int k = 0; k < D; ++k) pre += s_last[k] * W_pvsd[(D + k) * D + t];
        float hv = tanhf(pre);
        short hi = bf16rne(hv);
        short lo = bf16rne(hv - bf16f(hi));
        hh[b * D + t] = hi;
        hl[b * D + t] = lo;
    }
}

// K5m (R23 structure + ONE change): three block roles —
//   [0, NVB):            P_v (bf16x3 MFMA, h in LDS, VT=2). Single
//                        experiment: the 8 emb f4v loads are hoisted ABOVE
//                        the LDS stage, so the barrier's mandatory vmcnt(0)
//                        drain covers their HBM latency (R24 bundled this
//                        with the gnn fold, which regressed — the fold put
//                        scattered gathers on the 782 critical-path blocks;
//                        reverted: gnn stays in its own trailing blocks).
//   [NVB, NVB+NIB):      infomax partials (session rows direct from emb).
//   [NVB+NIB, +NGB):     gnn broadcast write (filler blocks, off the
//                        critical path).
__global__ __launch_bounds__(256, 4) void k5_mfma(
    const short* __restrict__ hh, const short* __restrict__ hl,
    const float* __restrict__ emb_i, const float* __restrict__ u,
    const int* __restrict__ nodes, float* __restrict__ gnn,
    float* __restrict__ pv, float* __restrict__ loss)
{
    __shared__ short slds[B * 128];   // 32KB

    const int t = threadIdx.x;

    if (blockIdx.x >= NVB + NIB) {
        // ---- gnn broadcast-write branch (former k0) ----
        const int idx = (blockIdx.x - NVB - NIB) * 256 + t;   // float4 index
        const int d4   = idx & (D / 4 - 1);
        const int rest = idx >> 4;
        const int l    = rest % L;
        const int bn   = rest / L;
        const int b    = bn >> 2;
        const int node = nodes[b * L + l];
        reinterpret_cast<float4*>(gnn)[idx] =
            reinterpret_cast<const float4*>(emb_i)[node * (D / 4) + d4];
        return;
    }

    if (blockIdx.x >= NVB) {
        // ---- infomax branch (former k3), session rows from emb ----
        const int b = blockIdx.x - NVB;
        float* s_up = reinterpret_cast<float*>(slds);        // [D]
        float* s_un = s_up + D;                              // [D]
        int*   s_nd = reinterpret_cast<int*>(s_un + D);      // [L]
        if (t < D) {
            const int bm1 = (b + B - 1) % B;
            s_up[t] = u[b * D + t];
            s_un[t] = u[bm1 * D + t];
        }
        if (t < L) s_nd[t] = nodes[b * L + t];
        __syncthreads();
        if (t < 64) {
            float lsp = 0.f, lsn = 0.f;
            if (t < L) {
                const float* se = emb_i + (size_t)s_nd[t] * D;   // == gnn n=0
                float sp = 0.f, sn = 0.f;
                #pragma unroll
                for (int d2 = 0; d2 < D; ++d2) {
                    float vv = se[d2];
                    sp += vv * s_up[d2];
                    sn += vv * s_un[d2];
                }
                lsp = log_sigmoid(sp);
                lsn = log_sigmoid(-sn);
            }
            float tot = lsp + lsn;
            for (int off = 32; off > 0; off >>= 1) tot += __shfl_down(tot, off);
            if (t == 0) atomicAdd(loss, -tot / (float)(B * L));
        }
        return;
    }

    // ---- P_v branch ----
    const int lane = t & 63;
    const int wid  = t >> 6;
    const int lm   = lane & 15;
    const int lg   = lane >> 4;
    const int v0   = (blockIdx.x * 8 + wid * 2) * 16;   // two tiles: v0, v0+16
    const int vcA  = v0 + lm;
    const int vcB  = v0 + 16 + lm;
    const int vldA = vcA < V ? vcA : (V - 1);
    const int vldB = vcB < V ? vcB : (V - 1);

    // emb loads FIRST — independent of the stage; barrier drain hides them
    const float* epA = emb_i + (size_t)vldA * D + 8 * lg;
    const float* epB = emb_i + (size_t)vldB * D + 8 * lg;
    f4v ea0 = *(const f4v*)(epA),      ea1 = *(const f4v*)(epA + 4);
    f4v ea2 = *(const f4v*)(epA + 32), ea3 = *(const f4v*)(epA + 36);
    f4v eb0 = *(const f4v*)(epB),      eb1 = *(const f4v*)(epB + 4);
    f4v eb2 = *(const f4v*)(epB + 32), eb3 = *(const f4v*)(epB + 36);

    // stage h-panel into LDS (XOR-swizzled quads)
    #pragma unroll
    for (int k = 0; k < 8; ++k) {
        const int i   = k * 256 + t;          // quad index 0..2047
        const int row = i >> 4;
        const int q   = i & 15;
        const int p   = (q & 8) | ((q & 7) ^ (row & 7));
        const short* src = (q < 8 ? hh : hl) + row * D + (q & 7) * 8;
        *(s8v*)(&slds[row * 128 + p * 8]) = *(const s8v*)(src);
    }
    __syncthreads();

    s8v Ahi0, Alo0, Ahi1, Alo1;
    s8v Bhi0, Blo0, Bhi1, Blo1;
    #pragma unroll
    for (int i = 0; i < 4; ++i) {
        { float x = ea0[i]; short h = bf16rne(x); Ahi0[i]   = h; Alo0[i]   = bf16rne(x - bf16f(h)); }
        { float x = ea1[i]; short h = bf16rne(x); Ahi0[i+4] = h; Alo0[i+4] = bf16rne(x - bf16f(h)); }
        { float x = ea2[i]; short h = bf16rne(x); Ahi1[i]   = h; Alo1[i]   = bf16rne(x - bf16f(h)); }
        { float x = ea3[i]; short h = bf16rne(x); Ahi1[i+4] = h; Alo1[i+4] = bf16rne(x - bf16f(h)); }
        { float x = eb0[i]; short h = bf16rne(x); Bhi0[i]   = h; Blo0[i]   = bf16rne(x - bf16f(h)); }
        { float x = eb1[i]; short h = bf16rne(x); Bhi0[i+4] = h; Blo0[i+4] = bf16rne(x - bf16f(h)); }
        { float x = eb2[i]; short h = bf16rne(x); Bhi1[i]   = h; Blo1[i]   = bf16rne(x - bf16f(h)); }
        { float x = eb3[i]; short h = bf16rne(x); Bhi1[i+4] = h; Blo1[i+4] = bf16rne(x - bf16f(h)); }
    }

    #pragma unroll
    for (int bt = 0; bt < 8; ++bt) {
        const int row = 16 * bt + lm;
        const int s   = lm & 7;
        const short* base = &slds[row * 128];
        s8v ah0 = *(const s8v*)(base + (((lg    ) ^ s) * 8));
        s8v ah1 = *(const s8v*)(base + (((lg + 4) ^ s) * 8));
        s8v al0 = *(const s8v*)(base + 64 + (((lg    ) ^ s) * 8));
        s8v al1 = *(const s8v*)(base + 64 + (((lg + 4) ^ s) * 8));
        f4v cA0 = {0.f,0.f,0.f,0.f}, cA1 = {0.f,0.f,0.f,0.f};
        f4v cB0 = {0.f,0.f,0.f,0.f}, cB1 = {0.f,0.f,0.f,0.f};
        cA0 = __builtin_amdgcn_mfma_f32_16x16x32_bf16(ah0, Ahi0, cA0, 0, 0, 0);
        cA1 = __builtin_amdgcn_mfma_f32_16x16x32_bf16(ah1, Ahi1, cA1, 0, 0, 0);
        cB0 = __builtin_amdgcn_mfma_f32_16x16x32_bf16(ah0, Bhi0, cB0, 0, 0, 0);
        cB1 = __builtin_amdgcn_mfma_f32_16x16x32_bf16(ah1, Bhi1, cB1, 0, 0, 0);
        cA0 = __builtin_amdgcn_mfma_f32_16x16x32_bf16(ah0, Alo0, cA0, 0, 0, 0);
        cA1 = __builtin_amdgcn_mfma_f32_16x16x32_bf16(ah1, Alo1, cA1, 0, 0, 0);
        cB0 = __builtin_amdgcn_mfma_f32_16x16x32_bf16(ah0, Blo0, cB0, 0, 0, 0);
        cB1 = __builtin_amdgcn_mfma_f32_16x16x32_bf16(ah1, Blo1, cB1, 0, 0, 0);
        cA0 = __builtin_amdgcn_mfma_f32_16x16x32_bf16(al0, Ahi0, cA0, 0, 0, 0);
        cA1 = __builtin_amdgcn_mfma_f32_16x16x32_bf16(al1, Ahi1, cA1, 0, 0, 0);
        cB0 = __builtin_amdgcn_mfma_f32_16x16x32_bf16(al0, Bhi0, cB0, 0, 0, 0);
        cB1 = __builtin_amdgcn_mfma_f32_16x16x32_bf16(al1, Bhi1, cB1, 0, 0, 0);
        const int br = 16 * bt + 4 * lg;
        if (vcA < V) {
            pv[(size_t)(br + 0) * V + vcA] = cA0[0] + cA1[0];
            pv[(size_t)(br + 1) * V + vcA] = cA0[1] + cA1[1];
            pv[(size_t)(br + 2) * V + vcA] = cA0[2] + cA1[2];
            pv[(size_t)(br + 3) * V + vcA] = cA0[3] + cA1[3];
        }
        if (vcB < V) {
            pv[(size_t)(br + 0) * V + vcB] = cB0[0] + cB1[0];
            pv[(size_t)(br + 1) * V + vcB] = cB0[1] + cB1[1];
            pv[(size_t)(br + 2) * V + vcB] = cB0[2] + cB1[2];
            pv[(size_t)(br + 3) * V + vcB] = cB0[3] + cB1[3];
        }
    }
}

extern "C" void kernel_launch(void* const* d_in, const int* in_sizes, int n_in,
                              void* d_out, int out_size, void* d_ws, size_t ws_size,
                              hipStream_t stream)
{
    const int*   nodes  = (const int*)d_in[0];
    const int*   sli    = (const int*)d_in[4];
    const int*   mask   = (const int*)d_in[6];
    const float* emb_i  = (const float*)d_in[7];
    const float* W_pvsd = (const float*)d_in[13];
    const float* b_pvsd = (const float*)d_in[14];
    const float* W_im   = (const float*)d_in[15];

    float* pv   = (float*)d_out;               // B*V
    float* loss = pv + (size_t)B * V;          // 1
    float* gnn  = loss + 1;                    // B*ND*L*D

    float* ws = (float*)d_ws;
    float* u  = ws;                            // B*D floats
    short* hh = (short*)(u + B * D);           // B*D bf16 hi
    short* hl = hh + B * D;                    // B*D bf16 lo

    k1_compute<<<B, 256, 0, stream>>>(nodes, mask, sli, emb_i, W_pvsd, b_pvsd,
                                      W_im, u, hh, hl, loss);
    k5_mfma<<<NVB + NIB + NGB, 256, 0, stream>>>(hh, hl, emb_i, u, nodes,
                                                 gnn, pv, loss);
}